// Round 1
// baseline (161.184 us; speedup 1.0000x reference)
//
#include <hip/hip_runtime.h>
#include <hip/hip_fp16.h>

// GLOBE_61864708931733 — R17: K=32 MFMA (L2/L3/out) + shared-rcp quad tanh.
// R16 post-mortem: pipe model matches counters EXACTLY under full serialization:
// trans 768*2 ops/wave @16cy = 98k cy/SIMD = 61% (=VALUBusy), MFMA 2816/SIMD
// @16.1cy = 45k = 28% (=MfmaUtil), main-VALU ~19k; sum = 162k cy = 67.6us wall.
// => no overlap headroom; cut cycles instead.
// R17a: mfma_f32_16x16x32_f16 for layers 2,3,out. C==B identity extends to
//   K=32: B-frag f16x8 = concat of two adjacent K=16 activation tiles; the
//   prep layout already stores A-units as the matching lo/hi k-pair, so the
//   slot<->k bijection is identical on both sides — prep kernel UNCHANGED.
//   MFMA/wave 704->384; matrix cy/SIMD 45k->29k.
// R17b: tpack computes 4 tanhs with ONE rcp (reciprocal of product, clamp
//   x<=30 so P<=2^120; tanh(30/SCALE)=1-1e-9). Trans/wave 1540->1040.
// Predicted: globe_mfma ~56-58us, MfmaUtil ~21%, VALUBusy ~77%.

#define N_T 2048
#define N_S 512
#define BLK 128
#define SCALE 2.885390081777927f   // 2*log2(e)

// d_ws: 4 copies, stride 5888 floats (23552 B):
//   units 0..21: f16x4-frag pairs, unit u = [64 lanes][16 B]
//     u 0..1:  W1 (unit0: mt0 lo / mt1 hi; unit1: mt2/mt3), kt=0 only
//     u 2..9:  W2: unit 2+mt*2+kp = frags (mt, kt=2kp) lo / (mt, 2kp+1) hi
//              == the K=32 frag for (mt, kk=kp) read as f16x8
//     u 10..17: W3 same
//     u 18..19: Wout hi | u 20..21: Wout lo
//   floats 5632..5823: scaled biases [3][64]
#define CPY_F 5888     // floats per copy
#define CPY_U 1472     // 16B units per copy

typedef _Float16 f16;
typedef _Float16 f16x4 __attribute__((ext_vector_type(4)));
typedef _Float16 f16x8 __attribute__((ext_vector_type(8)));
typedef float f32x4 __attribute__((ext_vector_type(4)));
typedef unsigned short u16;
typedef unsigned int u32;

__device__ __forceinline__ f32x4 mfma16(f16x4 a, f16x4 b, f32x4 c) {
    return __builtin_amdgcn_mfma_f32_16x16x16f16(a, b, c, 0, 0, 0);
}
__device__ __forceinline__ f32x4 mfma32(f16x8 a, f16x8 b, f32x4 c) {
    return __builtin_amdgcn_mfma_f32_16x16x32_f16(a, b, c, 0, 0, 0);
}

__device__ __forceinline__ u32 pkrtz(float a, float b) {
    return __builtin_bit_cast(u32, __builtin_amdgcn_cvt_pkrtz(a, b));
}

__device__ __forceinline__ f16x4 lo4(uint4 g) {
    uint2 p; p.x = g.x; p.y = g.y;
    return __builtin_bit_cast(f16x4, p);
}
__device__ __forceinline__ f16x4 hi4(uint4 g) {
    uint2 p; p.x = g.z; p.y = g.w;
    return __builtin_bit_cast(f16x4, p);
}
__device__ __forceinline__ f16x8 all8(uint4 g) {
    return __builtin_bit_cast(f16x8, g);
}
__device__ __forceinline__ f16x8 cat8(f16x4 a, f16x4 b) {
    return __builtin_shufflevector(a, b, 0, 1, 2, 3, 4, 5, 6, 7);
}

// quad tanh + pack: 4 tanhs share ONE rcp. x is pre-scaled by 2*log2(e):
// tanh = 1 - 2/(exp2(x)+1). Clamp x<=30 => each (e+1)<=2^30, product<=2^120
// (no overflow); tanh(30/SCALE) = 1-1.1e-9 so clamp is exact at f16.
__device__ __forceinline__ f16x4 tpack(f32x4 c) {
    const float a0 = __builtin_amdgcn_exp2f(fminf(c[0], 30.f)) + 1.f;
    const float a1 = __builtin_amdgcn_exp2f(fminf(c[1], 30.f)) + 1.f;
    const float a2 = __builtin_amdgcn_exp2f(fminf(c[2], 30.f)) + 1.f;
    const float a3 = __builtin_amdgcn_exp2f(fminf(c[3], 30.f)) + 1.f;
    const float p01 = a0 * a1, p23 = a2 * a3;
    const float r = __builtin_amdgcn_rcpf(p01 * p23);
    const float r01 = r * p23, r23 = r * p01;     // 1/(a0*a1), 1/(a2*a3)
    const float t0 = fmaf(-2.f, r01 * a1, 1.f);
    const float t1 = fmaf(-2.f, r01 * a0, 1.f);
    const float t2 = fmaf(-2.f, r23 * a3, 1.f);
    const float t3 = fmaf(-2.f, r23 * a2, 1.f);
    uint2 p;
    p.x = pkrtz(t0, t1);
    p.y = pkrtz(t2, t3);
    return __builtin_bit_cast(f16x4, p);
}

__global__ __launch_bounds__(256) void prep_kernel(
    const float* __restrict__ W1, const float* __restrict__ b1,
    const float* __restrict__ W2, const float* __restrict__ b2,
    const float* __restrict__ W3, const float* __restrict__ b3,
    const float* __restrict__ Wout, float* __restrict__ ws)
{
    const int tid = blockIdx.x * 256 + threadIdx.x;   // grid 25*256 = 6400
    if (tid < 5632) {                                 // 4 copies * 22 units * 64
        const int cpy = tid / 1408;
        const int r   = tid - cpy * 1408;
        const int u   = r >> 6, lane = r & 63;
        const int q = lane >> 4, l15 = lane & 15;
        float x[8];
        bool lo = false;
        #pragma unroll
        for (int e = 0; e < 8; ++e) {
            const int half = e >> 2, j = e & 3;
            float v;
            if (u < 2) {                       // W1: kt=0; frags mt = u*2+half
                const int mt = u * 2 + half;
                const int k = q * 4 + j;
                v = (k < 7) ? W1[k * 64 + mt * 16 + l15] * SCALE : 0.f;
            } else if (u < 10) {               // W2
                const int idx = u - 2, mt = idx >> 1, kp = idx & 1;
                const int k = (kp * 2 + half) * 16 + q * 4 + j;
                v = W2[k * 64 + mt * 16 + l15] * SCALE;
            } else if (u < 18) {               // W3
                const int idx = u - 10, mt = idx >> 1, kp = idx & 1;
                const int k = (kp * 2 + half) * 16 + q * 4 + j;
                v = W3[k * 64 + mt * 16 + l15] * SCALE;
            } else {                           // Wout hi (18,19) / lo (20,21)
                const int kp = (u - 18) & 1;
                const int k = (kp * 2 + half) * 16 + q * 4 + j;
                v = (l15 < 3) ? Wout[k * 3 + l15] : 0.f;
                lo = (u >= 20);
            }
            x[e] = v;
        }
        u16 outw[8];
        #pragma unroll
        for (int e = 0; e < 8; ++e) {
            const f16 h = (f16)x[e];
            const f16 val = lo ? (f16)(x[e] - (float)h) : h;
            outw[e] = __builtin_bit_cast(u16, val);
        }
        uint4 g;
        g.x = outw[0] | ((u32)outw[1] << 16);
        g.y = outw[2] | ((u32)outw[3] << 16);
        g.z = outw[4] | ((u32)outw[5] << 16);
        g.w = outw[6] | ((u32)outw[7] << 16);
        *(uint4*)((char*)ws + (size_t)cpy * CPY_F * 4 + (size_t)(u * 64 + lane) * 16) = g;
    } else {                                   // biases: 4 copies * 192
        const int b = tid - 5632;
        const int cpy = b / 192, i = b - cpy * 192;
        const int Lb = i >> 6, j = i & 63;
        float bv;
        if (Lb == 0)      bv = b1[j];
        else if (Lb == 1) bv = b2[j];
        else              bv = b3[j];
        ws[cpy * CPY_F + 5632 + i] = bv * SCALE;
    }
}

__global__ __launch_bounds__(BLK, 2) void globe_mfma(
    const float* __restrict__ pts, const float* __restrict__ ctr,
    const float* __restrict__ nrm, const float* __restrict__ areas,
    const float* __restrict__ rlen, const float* __restrict__ bout,
    const float* __restrict__ p_scale, const float* __restrict__ p_bias,
    const float* __restrict__ v_scale, const float* __restrict__ v_bias,
    const float* __restrict__ ws,
    float* __restrict__ out)
{
    __shared__ __align__(16) u16 featL[2][2][64][8];   // [wave][stream]
    __shared__ __align__(16) uint4 geomL[2][2][64];
    __shared__ float xr[4];

    const int tid  = threadIdx.x;
    const int lane = tid & 63;
    const int wv   = tid >> 6;
    const int l15  = lane & 15;
    const int q    = lane >> 4;
    const int qf   = q & 1;                          // clamped feature octet
    const int t    = blockIdx.x;                     // both waves: same target

    const float px = pts[3 * t + 0], py = pts[3 * t + 1], pz = pts[3 * t + 2];
    const float invL0 = __builtin_amdgcn_rcpf(rlen[0]);
    const float invL1 = __builtin_amdgcn_rcpf(rlen[1]);
    f32x4 co_init = (f32x4){0.f, 0.f, 0.f, 0.f};
    if (q == 0) { co_init[0] = bout[0]; co_init[1] = bout[1]; co_init[2] = bout[2]; }

    const f16x4 bz = (f16x4){0, 0, 0, 0};
    float accp = 0.f, avx = 0.f, avy = 0.f, avz = 0.f;

    #pragma unroll 1
    for (int ch = 0; ch < 2; ++ch) {
        // chunk-dependent weight copy (copies 0,2 used): defeats LICM
        const uint4* __restrict__ wsU = (const uint4*)ws + (ch * 2) * CPY_U;
        const float* __restrict__ wsBias = ws + (ch * 2) * CPY_F + 5632;

        // ---- features + geometry for BOTH streams ----
        #pragma unroll
        for (int st = 0; st < 2; ++st) {
            const int s = (wv * 4 + ch * 2 + st) * 64 + lane;
            const float cx = ctr[3 * s + 0], cy = ctr[3 * s + 1], cz = ctr[3 * s + 2];
            const float snx = nrm[3 * s + 0], sny = nrm[3 * s + 1], snz = nrm[3 * s + 2];
            const float ar = areas[s];
            const float rvx = px - cx, rvy = py - cy, rvz = pz - cz;
            const float r2 = rvx * rvx + rvy * rvy + rvz * rvz;
            const float r2e = r2 + 1e-8f;
            const float rinv = __builtin_amdgcn_rsqf(r2e);
            const float r = r2e * rinv;
            const float rhx = rvx * rinv, rhy = rvy * rinv, rhz = rvz * rinv;
            const float cth = rhx * snx + rhy * sny + rhz * snz;
            const float c2 = cth * cth;
            const float decay = ar * __builtin_amdgcn_rcpf(r2 + 1.0f);
            uint4 fw;
            fw.x = pkrtz(__builtin_amdgcn_rcpf(fmaf(r, invL0, 1.0f)),
                         __builtin_amdgcn_rcpf(fmaf(r, invL1, 1.0f)));
            fw.y = pkrtz(1.0f, cth);
            fw.z = pkrtz(fmaf(1.5f, c2, -0.5f), cth * fmaf(2.5f, c2, -1.5f));
            fw.w = pkrtz(__logf(ar), 0.0f);
            *(uint4*)&featL[wv][st][lane][0] = fw;
            uint4 g;
            g.x = __builtin_bit_cast(u32, decay);
            g.y = pkrtz(rhx, rhy);
            g.z = pkrtz(rhz, snx);
            g.w = pkrtz(sny, snz);
            geomL[wv][st][lane] = g;
        }

        // ---- layer 1 (16x16x16, K=7 padded; shared frags, both streams) ----
        f16x8 B2[2][2][4];   // [stream][kk][n4]  (K=32 frags for layer 2)
        {
            const uint4 g0 = wsU[0 * 64 + lane], g1 = wsU[1 * 64 + lane];
            f16x4 a1[4];
            a1[0] = lo4(g0); a1[1] = hi4(g0); a1[2] = lo4(g1); a1[3] = hi4(g1);
            float4 bv[4];
            #pragma unroll
            for (int mt = 0; mt < 4; ++mt)
                bv[mt] = *(const float4*)(wsBias + 0 * 64 + mt * 16 + q * 4);
            #pragma unroll
            for (int n4 = 0; n4 < 4; ++n4) {
                f16x4 bf[2];
                #pragma unroll
                for (int st = 0; st < 2; ++st) {
                    const f16x4 lv = *(const f16x4*)&featL[wv][st][n4 * 16 + l15][qf * 4];
                    bf[st] = (q < 2) ? lv : bz;
                }
                f32x4 c[2][4];
                #pragma unroll
                for (int mt = 0; mt < 4; ++mt) {
                    c[0][mt] = (f32x4){bv[mt].x, bv[mt].y, bv[mt].z, bv[mt].w};
                    c[1][mt] = c[0][mt];
                    c[0][mt] = mfma16(a1[mt], bf[0], c[0][mt]);
                    c[1][mt] = mfma16(a1[mt], bf[1], c[1][mt]);
                }
                #pragma unroll
                for (int kk = 0; kk < 2; ++kk) {
                    B2[0][kk][n4] = cat8(tpack(c[0][2 * kk]), tpack(c[0][2 * kk + 1]));
                    B2[1][kk][n4] = cat8(tpack(c[1][2 * kk]), tpack(c[1][2 * kk + 1]));
                }
            }
        }

        // ---- layer 2 (16x16x32) ----
        f16x8 B3[2][2][4];
        {
            f16x8 a[4][2];
            #pragma unroll
            for (int mt = 0; mt < 4; ++mt) {
                a[mt][0] = all8(wsU[(2 + 2 * mt) * 64 + lane]);
                a[mt][1] = all8(wsU[(3 + 2 * mt) * 64 + lane]);
            }
            float4 bv[4];
            #pragma unroll
            for (int mt = 0; mt < 4; ++mt)
                bv[mt] = *(const float4*)(wsBias + 1 * 64 + mt * 16 + q * 4);
            #pragma unroll
            for (int n4 = 0; n4 < 4; ++n4) {
                f32x4 c[2][4];
                #pragma unroll
                for (int mt = 0; mt < 4; ++mt) {
                    c[0][mt] = (f32x4){bv[mt].x, bv[mt].y, bv[mt].z, bv[mt].w};
                    c[1][mt] = c[0][mt];
                }
                #pragma unroll
                for (int kk = 0; kk < 2; ++kk)
                    #pragma unroll
                    for (int mt = 0; mt < 4; ++mt) {
                        c[0][mt] = mfma32(a[mt][kk], B2[0][kk][n4], c[0][mt]);
                        c[1][mt] = mfma32(a[mt][kk], B2[1][kk][n4], c[1][mt]);
                    }
                #pragma unroll
                for (int kk = 0; kk < 2; ++kk) {
                    B3[0][kk][n4] = cat8(tpack(c[0][2 * kk]), tpack(c[0][2 * kk + 1]));
                    B3[1][kk][n4] = cat8(tpack(c[1][2 * kk]), tpack(c[1][2 * kk + 1]));
                }
            }
        }

        // ---- layer 3 (16x16x32) ----
        f16x8 BO[2][2][4];
        {
            f16x8 a[4][2];
            #pragma unroll
            for (int mt = 0; mt < 4; ++mt) {
                a[mt][0] = all8(wsU[(10 + 2 * mt) * 64 + lane]);
                a[mt][1] = all8(wsU[(11 + 2 * mt) * 64 + lane]);
            }
            float4 bv[4];
            #pragma unroll
            for (int mt = 0; mt < 4; ++mt)
                bv[mt] = *(const float4*)(wsBias + 2 * 64 + mt * 16 + q * 4);
            #pragma unroll
            for (int n4 = 0; n4 < 4; ++n4) {
                f32x4 c[2][4];
                #pragma unroll
                for (int mt = 0; mt < 4; ++mt) {
                    c[0][mt] = (f32x4){bv[mt].x, bv[mt].y, bv[mt].z, bv[mt].w};
                    c[1][mt] = c[0][mt];
                }
                #pragma unroll
                for (int kk = 0; kk < 2; ++kk)
                    #pragma unroll
                    for (int mt = 0; mt < 4; ++mt) {
                        c[0][mt] = mfma32(a[mt][kk], B3[0][kk][n4], c[0][mt]);
                        c[1][mt] = mfma32(a[mt][kk], B3[1][kk][n4], c[1][mt]);
                    }
                #pragma unroll
                for (int kk = 0; kk < 2; ++kk) {
                    BO[0][kk][n4] = cat8(tpack(c[0][2 * kk]), tpack(c[0][2 * kk + 1]));
                    BO[1][kk][n4] = cat8(tpack(c[1][2 * kk]), tpack(c[1][2 * kk + 1]));
                }
            }
        }

        // ---- output layer (16x16x32, hi+lo) + decay-weighted accumulation ----
        {
            const f16x8 aoh0 = all8(wsU[18 * 64 + lane]);
            const f16x8 aoh1 = all8(wsU[19 * 64 + lane]);
            const f16x8 aol0 = all8(wsU[20 * 64 + lane]);
            const f16x8 aol1 = all8(wsU[21 * 64 + lane]);
            #pragma unroll
            for (int n4 = 0; n4 < 4; ++n4) {
                f32x4 co[2];
                co[0] = co_init; co[1] = co_init;
                co[0] = mfma32(aoh0, BO[0][0][n4], co[0]);
                co[1] = mfma32(aoh0, BO[1][0][n4], co[1]);
                co[0] = mfma32(aol0, BO[0][0][n4], co[0]);
                co[1] = mfma32(aol0, BO[1][0][n4], co[1]);
                co[0] = mfma32(aoh1, BO[0][1][n4], co[0]);
                co[1] = mfma32(aoh1, BO[1][1][n4], co[1]);
                co[0] = mfma32(aol1, BO[0][1][n4], co[0]);
                co[1] = mfma32(aol1, BO[1][1][n4], co[1]);
                if (q == 0) {
                    #pragma unroll
                    for (int st = 0; st < 2; ++st) {
                        const uint4 g = geomL[wv][st][n4 * 16 + l15];
                        const float d = __builtin_bit_cast(float, g.x);
                        const float2 rxy = __half22float2(__builtin_bit_cast(__half2, g.y));
                        const float2 rzx = __half22float2(__builtin_bit_cast(__half2, g.z));
                        const float2 nyz = __half22float2(__builtin_bit_cast(__half2, g.w));
                        const float o0 = co[st][0], o1 = co[st][1], o2 = co[st][2];
                        accp = fmaf(o0, d, accp);
                        avx  = fmaf(fmaf(o1, rxy.x, o2 * rzx.y), d, avx);
                        avy  = fmaf(fmaf(o1, rxy.y, o2 * nyz.x), d, avy);
                        avz  = fmaf(fmaf(o1, rzx.x, o2 * nyz.y), d, avz);
                    }
                }
            }
        }
    }

    // ---- reduce across the 16 accumulating lanes ----
    #pragma unroll
    for (int off = 8; off > 0; off >>= 1) {
        accp += __shfl_down(accp, off);
        avx  += __shfl_down(avx,  off);
        avy  += __shfl_down(avy,  off);
        avz  += __shfl_down(avz,  off);
    }

    // ---- cross-wave combine ----
    if (wv == 1 && lane == 0) {
        xr[0] = accp; xr[1] = avx; xr[2] = avy; xr[3] = avz;
    }
    __syncthreads();
    if (wv == 0 && lane == 0) {
        accp += xr[0]; avx += xr[1]; avy += xr[2]; avz += xr[3];
        const float ps = p_scale[0], pb = p_bias[0];
        const float vs = v_scale[0], vb = v_bias[0];
        out[4 * t + 0] = fmaf(accp, ps, pb);
        out[4 * t + 1] = fmaf(avx, vs, vb);
        out[4 * t + 2] = fmaf(avy, vs, vb);
        out[4 * t + 3] = fmaf(avz, vs, vb);
    }
}

extern "C" void kernel_launch(void* const* d_in, const int* in_sizes, int n_in,
                              void* d_out, int out_size, void* d_ws, size_t ws_size,
                              hipStream_t stream) {
    (void)in_sizes; (void)n_in; (void)ws_size; (void)out_size;
    const float* pts   = (const float*)d_in[0];
    const float* ctr   = (const float*)d_in[1];
    const float* nrm   = (const float*)d_in[2];
    const float* areas = (const float*)d_in[3];
    const float* rlen  = (const float*)d_in[4];
    const float* W1    = (const float*)d_in[5];
    const float* b1    = (const float*)d_in[6];
    const float* W2    = (const float*)d_in[7];
    const float* b2    = (const float*)d_in[8];
    const float* W3    = (const float*)d_in[9];
    const float* b3    = (const float*)d_in[10];
    const float* Wout  = (const float*)d_in[11];
    const float* bout  = (const float*)d_in[12];
    const float* ps    = (const float*)d_in[13];
    const float* pb    = (const float*)d_in[14];
    const float* vs    = (const float*)d_in[15];
    const float* vb    = (const float*)d_in[16];
    float* ws = (float*)d_ws;

    prep_kernel<<<25, 256, 0, stream>>>(W1, b1, W2, b2, W3, b3, Wout, ws);
    globe_mfma<<<N_T, BLK, 0, stream>>>(
        pts, ctr, nrm, areas, rlen, bout, ps, pb, vs, vb, ws, (float*)d_out);
}

// Round 2
// 144.540 us; speedup vs baseline: 1.1151x; 1.1151x over previous
//
#include <hip/hip_runtime.h>
#include <hip/hip_fp16.h>

// GLOBE_61864708931733 — R18: keep K=32 MFMA, revert tanh to simple form,
// form f16x8 B-frags directly from uint4 (no shufflevector glue).
// R17 post-mortem (85.6us, regression): MFMA pipe cycles DID halve
// (45k->24.4k cy/SIMD; 16x16x16_f16 is half-rate, 16x16x32_f16 full-rate,
// both ~16cy pipe occupancy). Regression was VALU: +28k busy (quad-rcp adds
// ~13 ops/tpack; v_rcp is ~free, v_exp ~26cy, so sharing rcp saved nothing)
// + cat8 shufflevector glue + longer tpack serial chain (+36k idle).
// R18: simple exp2+rcp tanh (R16's), tpack8 builds uint4 -> f16x8 directly.
// Predicted: ~58-60us, MfmaUtil ~17%, VALUBusy ~71%, absmax 0.25.

#define N_T 2048
#define N_S 512
#define BLK 128
#define SCALE 2.885390081777927f   // 2*log2(e)

// d_ws: 4 copies, stride 5888 floats (23552 B):
//   units 0..21: f16x4-frag pairs, unit u = [64 lanes][16 B]
//     u 0..1:  W1 (unit0: mt0 lo / mt1 hi; unit1: mt2/mt3), kt=0 only
//     u 2..9:  W2: unit 2+mt*2+kp = frags (mt, kt=2kp) lo / (mt, 2kp+1) hi
//              == the K=32 frag for (mt, kk=kp) read as f16x8
//     u 10..17: W3 same
//     u 18..19: Wout hi | u 20..21: Wout lo
//   floats 5632..5823: scaled biases [3][64]
#define CPY_F 5888     // floats per copy
#define CPY_U 1472     // 16B units per copy

typedef _Float16 f16;
typedef _Float16 f16x4 __attribute__((ext_vector_type(4)));
typedef _Float16 f16x8 __attribute__((ext_vector_type(8)));
typedef float f32x4 __attribute__((ext_vector_type(4)));
typedef unsigned short u16;
typedef unsigned int u32;

__device__ __forceinline__ float tanh_s(float x) {
    // x is already SCALE*y; tanh(y) = 1 - 2/(exp2(x)+1). Saturates exactly.
    float e = __builtin_amdgcn_exp2f(x);
    return fmaf(-2.0f, __builtin_amdgcn_rcpf(e + 1.0f), 1.0f);
}

__device__ __forceinline__ f32x4 mfma16(f16x4 a, f16x4 b, f32x4 c) {
    return __builtin_amdgcn_mfma_f32_16x16x16f16(a, b, c, 0, 0, 0);
}
__device__ __forceinline__ f32x4 mfma32(f16x8 a, f16x8 b, f32x4 c) {
    return __builtin_amdgcn_mfma_f32_16x16x32_f16(a, b, c, 0, 0, 0);
}

__device__ __forceinline__ u32 pkrtz(float a, float b) {
    return __builtin_bit_cast(u32, __builtin_amdgcn_cvt_pkrtz(a, b));
}

__device__ __forceinline__ f16x4 lo4(uint4 g) {
    uint2 p; p.x = g.x; p.y = g.y;
    return __builtin_bit_cast(f16x4, p);
}
__device__ __forceinline__ f16x4 hi4(uint4 g) {
    uint2 p; p.x = g.z; p.y = g.w;
    return __builtin_bit_cast(f16x4, p);
}
__device__ __forceinline__ f16x8 all8(uint4 g) {
    return __builtin_bit_cast(f16x8, g);
}

// 8 tanhs -> one K=32 B-frag (f16x8) built directly as a uint4.
__device__ __forceinline__ f16x8 tpack8(f32x4 cl, f32x4 ch) {
    uint4 p;
    p.x = pkrtz(tanh_s(cl[0]), tanh_s(cl[1]));
    p.y = pkrtz(tanh_s(cl[2]), tanh_s(cl[3]));
    p.z = pkrtz(tanh_s(ch[0]), tanh_s(ch[1]));
    p.w = pkrtz(tanh_s(ch[2]), tanh_s(ch[3]));
    return __builtin_bit_cast(f16x8, p);
}

__global__ __launch_bounds__(256) void prep_kernel(
    const float* __restrict__ W1, const float* __restrict__ b1,
    const float* __restrict__ W2, const float* __restrict__ b2,
    const float* __restrict__ W3, const float* __restrict__ b3,
    const float* __restrict__ Wout, float* __restrict__ ws)
{
    const int tid = blockIdx.x * 256 + threadIdx.x;   // grid 25*256 = 6400
    if (tid < 5632) {                                 // 4 copies * 22 units * 64
        const int cpy = tid / 1408;
        const int r   = tid - cpy * 1408;
        const int u   = r >> 6, lane = r & 63;
        const int q = lane >> 4, l15 = lane & 15;
        float x[8];
        bool lo = false;
        #pragma unroll
        for (int e = 0; e < 8; ++e) {
            const int half = e >> 2, j = e & 3;
            float v;
            if (u < 2) {                       // W1: kt=0; frags mt = u*2+half
                const int mt = u * 2 + half;
                const int k = q * 4 + j;
                v = (k < 7) ? W1[k * 64 + mt * 16 + l15] * SCALE : 0.f;
            } else if (u < 10) {               // W2
                const int idx = u - 2, mt = idx >> 1, kp = idx & 1;
                const int k = (kp * 2 + half) * 16 + q * 4 + j;
                v = W2[k * 64 + mt * 16 + l15] * SCALE;
            } else if (u < 18) {               // W3
                const int idx = u - 10, mt = idx >> 1, kp = idx & 1;
                const int k = (kp * 2 + half) * 16 + q * 4 + j;
                v = W3[k * 64 + mt * 16 + l15] * SCALE;
            } else {                           // Wout hi (18,19) / lo (20,21)
                const int kp = (u - 18) & 1;
                const int k = (kp * 2 + half) * 16 + q * 4 + j;
                v = (l15 < 3) ? Wout[k * 3 + l15] : 0.f;
                lo = (u >= 20);
            }
            x[e] = v;
        }
        u16 outw[8];
        #pragma unroll
        for (int e = 0; e < 8; ++e) {
            const f16 h = (f16)x[e];
            const f16 val = lo ? (f16)(x[e] - (float)h) : h;
            outw[e] = __builtin_bit_cast(u16, val);
        }
        uint4 g;
        g.x = outw[0] | ((u32)outw[1] << 16);
        g.y = outw[2] | ((u32)outw[3] << 16);
        g.z = outw[4] | ((u32)outw[5] << 16);
        g.w = outw[6] | ((u32)outw[7] << 16);
        *(uint4*)((char*)ws + (size_t)cpy * CPY_F * 4 + (size_t)(u * 64 + lane) * 16) = g;
    } else {                                   // biases: 4 copies * 192
        const int b = tid - 5632;
        const int cpy = b / 192, i = b - cpy * 192;
        const int Lb = i >> 6, j = i & 63;
        float bv;
        if (Lb == 0)      bv = b1[j];
        else if (Lb == 1) bv = b2[j];
        else              bv = b3[j];
        ws[cpy * CPY_F + 5632 + i] = bv * SCALE;
    }
}

__global__ __launch_bounds__(BLK, 2) void globe_mfma(
    const float* __restrict__ pts, const float* __restrict__ ctr,
    const float* __restrict__ nrm, const float* __restrict__ areas,
    const float* __restrict__ rlen, const float* __restrict__ bout,
    const float* __restrict__ p_scale, const float* __restrict__ p_bias,
    const float* __restrict__ v_scale, const float* __restrict__ v_bias,
    const float* __restrict__ ws,
    float* __restrict__ out)
{
    __shared__ __align__(16) u16 featL[2][2][64][8];   // [wave][stream]
    __shared__ __align__(16) uint4 geomL[2][2][64];
    __shared__ float xr[4];

    const int tid  = threadIdx.x;
    const int lane = tid & 63;
    const int wv   = tid >> 6;
    const int l15  = lane & 15;
    const int q    = lane >> 4;
    const int qf   = q & 1;                          // clamped feature octet
    const int t    = blockIdx.x;                     // both waves: same target

    const float px = pts[3 * t + 0], py = pts[3 * t + 1], pz = pts[3 * t + 2];
    const float invL0 = __builtin_amdgcn_rcpf(rlen[0]);
    const float invL1 = __builtin_amdgcn_rcpf(rlen[1]);
    f32x4 co_init = (f32x4){0.f, 0.f, 0.f, 0.f};
    if (q == 0) { co_init[0] = bout[0]; co_init[1] = bout[1]; co_init[2] = bout[2]; }

    const f16x4 bz = (f16x4){0, 0, 0, 0};
    float accp = 0.f, avx = 0.f, avy = 0.f, avz = 0.f;

    #pragma unroll 1
    for (int ch = 0; ch < 2; ++ch) {
        // chunk-dependent weight copy (copies 0,2 used): defeats LICM
        const uint4* __restrict__ wsU = (const uint4*)ws + (ch * 2) * CPY_U;
        const float* __restrict__ wsBias = ws + (ch * 2) * CPY_F + 5632;

        // ---- features + geometry for BOTH streams ----
        #pragma unroll
        for (int st = 0; st < 2; ++st) {
            const int s = (wv * 4 + ch * 2 + st) * 64 + lane;
            const float cx = ctr[3 * s + 0], cy = ctr[3 * s + 1], cz = ctr[3 * s + 2];
            const float snx = nrm[3 * s + 0], sny = nrm[3 * s + 1], snz = nrm[3 * s + 2];
            const float ar = areas[s];
            const float rvx = px - cx, rvy = py - cy, rvz = pz - cz;
            const float r2 = rvx * rvx + rvy * rvy + rvz * rvz;
            const float r2e = r2 + 1e-8f;
            const float rinv = __builtin_amdgcn_rsqf(r2e);
            const float r = r2e * rinv;
            const float rhx = rvx * rinv, rhy = rvy * rinv, rhz = rvz * rinv;
            const float cth = rhx * snx + rhy * sny + rhz * snz;
            const float c2 = cth * cth;
            const float decay = ar * __builtin_amdgcn_rcpf(r2 + 1.0f);
            uint4 fw;
            fw.x = pkrtz(__builtin_amdgcn_rcpf(fmaf(r, invL0, 1.0f)),
                         __builtin_amdgcn_rcpf(fmaf(r, invL1, 1.0f)));
            fw.y = pkrtz(1.0f, cth);
            fw.z = pkrtz(fmaf(1.5f, c2, -0.5f), cth * fmaf(2.5f, c2, -1.5f));
            fw.w = pkrtz(__logf(ar), 0.0f);
            *(uint4*)&featL[wv][st][lane][0] = fw;
            uint4 g;
            g.x = __builtin_bit_cast(u32, decay);
            g.y = pkrtz(rhx, rhy);
            g.z = pkrtz(rhz, snx);
            g.w = pkrtz(sny, snz);
            geomL[wv][st][lane] = g;
        }

        // ---- layer 1 (16x16x16, K=7 padded; shared frags, both streams) ----
        f16x8 B2[2][2][4];   // [stream][kk][n4]  (K=32 frags for layer 2)
        {
            const uint4 g0 = wsU[0 * 64 + lane], g1 = wsU[1 * 64 + lane];
            f16x4 a1[4];
            a1[0] = lo4(g0); a1[1] = hi4(g0); a1[2] = lo4(g1); a1[3] = hi4(g1);
            float4 bv[4];
            #pragma unroll
            for (int mt = 0; mt < 4; ++mt)
                bv[mt] = *(const float4*)(wsBias + 0 * 64 + mt * 16 + q * 4);
            #pragma unroll
            for (int n4 = 0; n4 < 4; ++n4) {
                f16x4 bf[2];
                #pragma unroll
                for (int st = 0; st < 2; ++st) {
                    const f16x4 lv = *(const f16x4*)&featL[wv][st][n4 * 16 + l15][qf * 4];
                    bf[st] = (q < 2) ? lv : bz;
                }
                f32x4 c[2][4];
                #pragma unroll
                for (int mt = 0; mt < 4; ++mt) {
                    c[0][mt] = (f32x4){bv[mt].x, bv[mt].y, bv[mt].z, bv[mt].w};
                    c[1][mt] = c[0][mt];
                    c[0][mt] = mfma16(a1[mt], bf[0], c[0][mt]);
                    c[1][mt] = mfma16(a1[mt], bf[1], c[1][mt]);
                }
                #pragma unroll
                for (int kk = 0; kk < 2; ++kk) {
                    B2[0][kk][n4] = tpack8(c[0][2 * kk], c[0][2 * kk + 1]);
                    B2[1][kk][n4] = tpack8(c[1][2 * kk], c[1][2 * kk + 1]);
                }
            }
        }

        // ---- layer 2 (16x16x32) ----
        f16x8 B3[2][2][4];
        {
            f16x8 a[4][2];
            #pragma unroll
            for (int mt = 0; mt < 4; ++mt) {
                a[mt][0] = all8(wsU[(2 + 2 * mt) * 64 + lane]);
                a[mt][1] = all8(wsU[(3 + 2 * mt) * 64 + lane]);
            }
            float4 bv[4];
            #pragma unroll
            for (int mt = 0; mt < 4; ++mt)
                bv[mt] = *(const float4*)(wsBias + 1 * 64 + mt * 16 + q * 4);
            #pragma unroll
            for (int n4 = 0; n4 < 4; ++n4) {
                f32x4 c[2][4];
                #pragma unroll
                for (int mt = 0; mt < 4; ++mt) {
                    c[0][mt] = (f32x4){bv[mt].x, bv[mt].y, bv[mt].z, bv[mt].w};
                    c[1][mt] = c[0][mt];
                }
                #pragma unroll
                for (int kk = 0; kk < 2; ++kk)
                    #pragma unroll
                    for (int mt = 0; mt < 4; ++mt) {
                        c[0][mt] = mfma32(a[mt][kk], B2[0][kk][n4], c[0][mt]);
                        c[1][mt] = mfma32(a[mt][kk], B2[1][kk][n4], c[1][mt]);
                    }
                #pragma unroll
                for (int kk = 0; kk < 2; ++kk) {
                    B3[0][kk][n4] = tpack8(c[0][2 * kk], c[0][2 * kk + 1]);
                    B3[1][kk][n4] = tpack8(c[1][2 * kk], c[1][2 * kk + 1]);
                }
            }
        }

        // ---- layer 3 (16x16x32) ----
        f16x8 BO[2][2][4];
        {
            f16x8 a[4][2];
            #pragma unroll
            for (int mt = 0; mt < 4; ++mt) {
                a[mt][0] = all8(wsU[(10 + 2 * mt) * 64 + lane]);
                a[mt][1] = all8(wsU[(11 + 2 * mt) * 64 + lane]);
            }
            float4 bv[4];
            #pragma unroll
            for (int mt = 0; mt < 4; ++mt)
                bv[mt] = *(const float4*)(wsBias + 2 * 64 + mt * 16 + q * 4);
            #pragma unroll
            for (int n4 = 0; n4 < 4; ++n4) {
                f32x4 c[2][4];
                #pragma unroll
                for (int mt = 0; mt < 4; ++mt) {
                    c[0][mt] = (f32x4){bv[mt].x, bv[mt].y, bv[mt].z, bv[mt].w};
                    c[1][mt] = c[0][mt];
                }
                #pragma unroll
                for (int kk = 0; kk < 2; ++kk)
                    #pragma unroll
                    for (int mt = 0; mt < 4; ++mt) {
                        c[0][mt] = mfma32(a[mt][kk], B3[0][kk][n4], c[0][mt]);
                        c[1][mt] = mfma32(a[mt][kk], B3[1][kk][n4], c[1][mt]);
                    }
                #pragma unroll
                for (int kk = 0; kk < 2; ++kk) {
                    BO[0][kk][n4] = tpack8(c[0][2 * kk], c[0][2 * kk + 1]);
                    BO[1][kk][n4] = tpack8(c[1][2 * kk], c[1][2 * kk + 1]);
                }
            }
        }

        // ---- output layer (16x16x32, hi+lo) + decay-weighted accumulation ----
        {
            const f16x8 aoh0 = all8(wsU[18 * 64 + lane]);
            const f16x8 aoh1 = all8(wsU[19 * 64 + lane]);
            const f16x8 aol0 = all8(wsU[20 * 64 + lane]);
            const f16x8 aol1 = all8(wsU[21 * 64 + lane]);
            #pragma unroll
            for (int n4 = 0; n4 < 4; ++n4) {
                f32x4 co[2];
                co[0] = co_init; co[1] = co_init;
                co[0] = mfma32(aoh0, BO[0][0][n4], co[0]);
                co[1] = mfma32(aoh0, BO[1][0][n4], co[1]);
                co[0] = mfma32(aol0, BO[0][0][n4], co[0]);
                co[1] = mfma32(aol0, BO[1][0][n4], co[1]);
                co[0] = mfma32(aoh1, BO[0][1][n4], co[0]);
                co[1] = mfma32(aoh1, BO[1][1][n4], co[1]);
                co[0] = mfma32(aol1, BO[0][1][n4], co[0]);
                co[1] = mfma32(aol1, BO[1][1][n4], co[1]);
                if (q == 0) {
                    #pragma unroll
                    for (int st = 0; st < 2; ++st) {
                        const uint4 g = geomL[wv][st][n4 * 16 + l15];
                        const float d = __builtin_bit_cast(float, g.x);
                        const float2 rxy = __half22float2(__builtin_bit_cast(__half2, g.y));
                        const float2 rzx = __half22float2(__builtin_bit_cast(__half2, g.z));
                        const float2 nyz = __half22float2(__builtin_bit_cast(__half2, g.w));
                        const float o0 = co[st][0], o1 = co[st][1], o2 = co[st][2];
                        accp = fmaf(o0, d, accp);
                        avx  = fmaf(fmaf(o1, rxy.x, o2 * rzx.y), d, avx);
                        avy  = fmaf(fmaf(o1, rxy.y, o2 * nyz.x), d, avy);
                        avz  = fmaf(fmaf(o1, rzx.x, o2 * nyz.y), d, avz);
                    }
                }
            }
        }
    }

    // ---- reduce across the 16 accumulating lanes ----
    #pragma unroll
    for (int off = 8; off > 0; off >>= 1) {
        accp += __shfl_down(accp, off);
        avx  += __shfl_down(avx,  off);
        avy  += __shfl_down(avy,  off);
        avz  += __shfl_down(avz,  off);
    }

    // ---- cross-wave combine ----
    if (wv == 1 && lane == 0) {
        xr[0] = accp; xr[1] = avx; xr[2] = avy; xr[3] = avz;
    }
    __syncthreads();
    if (wv == 0 && lane == 0) {
        accp += xr[0]; avx += xr[1]; avy += xr[2]; avz += xr[3];
        const float ps = p_scale[0], pb = p_bias[0];
        const float vs = v_scale[0], vb = v_bias[0];
        out[4 * t + 0] = fmaf(accp, ps, pb);
        out[4 * t + 1] = fmaf(avx, vs, vb);
        out[4 * t + 2] = fmaf(avy, vs, vb);
        out[4 * t + 3] = fmaf(avz, vs, vb);
    }
}

extern "C" void kernel_launch(void* const* d_in, const int* in_sizes, int n_in,
                              void* d_out, int out_size, void* d_ws, size_t ws_size,
                              hipStream_t stream) {
    (void)in_sizes; (void)n_in; (void)ws_size; (void)out_size;
    const float* pts   = (const float*)d_in[0];
    const float* ctr   = (const float*)d_in[1];
    const float* nrm   = (const float*)d_in[2];
    const float* areas = (const float*)d_in[3];
    const float* rlen  = (const float*)d_in[4];
    const float* W1    = (const float*)d_in[5];
    const float* b1    = (const float*)d_in[6];
    const float* W2    = (const float*)d_in[7];
    const float* b2    = (const float*)d_in[8];
    const float* W3    = (const float*)d_in[9];
    const float* b3    = (const float*)d_in[10];
    const float* Wout  = (const float*)d_in[11];
    const float* bout  = (const float*)d_in[12];
    const float* ps    = (const float*)d_in[13];
    const float* pb    = (const float*)d_in[14];
    const float* vs    = (const float*)d_in[15];
    const float* vb    = (const float*)d_in[16];
    float* ws = (float*)d_ws;

    prep_kernel<<<25, 256, 0, stream>>>(W1, b1, W2, b2, W3, b3, Wout, ws);
    globe_mfma<<<N_T, BLK, 0, stream>>>(
        pts, ctr, nrm, areas, rlen, bout, ps, pb, vs, vb, ws, (float*)d_out);
}

// Round 3
// 132.189 us; speedup vs baseline: 1.2193x; 1.0934x over previous
//
#include <hip/hip_runtime.h>
#include <hip/hip_fp16.h>

// GLOBE_61864708931733 — R19: z-folding + chunk-order phase stagger.
// R18 post-mortem (64.7us): MFMA 23.7k cy/SIMD (K=32 dense-rate, win held),
// VALU busy 91.5k (fits exp2=16cy, rcp=8cy, fma=2cy model), idle 40k (26%).
// R16->R18 cut 30k issue cy but wall only -7k -> partially latency-bound:
// 4 phase-locked waves/SIMD stall on MFMA->tanh deps simultaneously.
// R19a z-fold: next layers consume z=1/(e+1) (t=1-2z) with W'=-2W*SCALE,
//   b'=(b+colsum(W))*SCALE folded in prep; tpack loses the fma (-6k cy/SIMD)
//   and the serial chain shortens by one op. bout'=bout+colsum(Wout) in ws.
// R19b stagger: ch = cc ^ ((wv+blockIdx)&1) -> co-resident waves in opposite
//   phases so dependency stalls interleave instead of aligning.
// Predicted: globe ~54-57us, VALUBusy ~63-66%, MfmaUtil ~17-18%, absmax same.

#define N_T 2048
#define N_S 512
#define BLK 128
#define SCALE 2.885390081777927f   // 2*log2(e)

// d_ws: 4 copies, stride 5888 floats (23552 B):
//   units 0..21: f16x4-frag pairs, unit u = [64 lanes][16 B]
//     u 0..1:  W1 (unit0: mt0 lo / mt1 hi; unit1: mt2/mt3), kt=0 only
//     u 2..9:  W2' = -2*W2*SCALE: unit 2+mt*2+kp = K=32 frag (mt, kk=kp) f16x8
//     u 10..17: W3' same
//     u 18..19: Wout' hi | u 20..21: Wout' lo   (Wout' = -2*Wout, unscaled)
//   floats 5632..5823: scaled biases [3][64]; b2',b3' include +colsum(W)
//   floats 5824..5826: bout' = bout + colsum(Wout)  (unscaled)
#define CPY_F 5888     // floats per copy
#define CPY_U 1472     // 16B units per copy

typedef _Float16 f16;
typedef _Float16 f16x4 __attribute__((ext_vector_type(4)));
typedef _Float16 f16x8 __attribute__((ext_vector_type(8)));
typedef float f32x4 __attribute__((ext_vector_type(4)));
typedef unsigned short u16;
typedef unsigned int u32;

__device__ __forceinline__ float zsig(float x) {
    // x is SCALE*y; z = 1/(2^x+1); consumer weights are folded so t = 1-2z.
    float e = __builtin_amdgcn_exp2f(x);
    return __builtin_amdgcn_rcpf(e + 1.0f);
}

__device__ __forceinline__ f32x4 mfma16(f16x4 a, f16x4 b, f32x4 c) {
    return __builtin_amdgcn_mfma_f32_16x16x16f16(a, b, c, 0, 0, 0);
}
__device__ __forceinline__ f32x4 mfma32(f16x8 a, f16x8 b, f32x4 c) {
    return __builtin_amdgcn_mfma_f32_16x16x32_f16(a, b, c, 0, 0, 0);
}

__device__ __forceinline__ u32 pkrtz(float a, float b) {
    return __builtin_bit_cast(u32, __builtin_amdgcn_cvt_pkrtz(a, b));
}

__device__ __forceinline__ f16x4 lo4(uint4 g) {
    uint2 p; p.x = g.x; p.y = g.y;
    return __builtin_bit_cast(f16x4, p);
}
__device__ __forceinline__ f16x4 hi4(uint4 g) {
    uint2 p; p.x = g.z; p.y = g.w;
    return __builtin_bit_cast(f16x4, p);
}
__device__ __forceinline__ f16x8 all8(uint4 g) {
    return __builtin_bit_cast(f16x8, g);
}

// 8 z-sigmoids -> one K=32 B-frag (f16x8) built directly as a uint4.
__device__ __forceinline__ f16x8 tpack8(f32x4 cl, f32x4 ch) {
    uint4 p;
    p.x = pkrtz(zsig(cl[0]), zsig(cl[1]));
    p.y = pkrtz(zsig(cl[2]), zsig(cl[3]));
    p.z = pkrtz(zsig(ch[0]), zsig(ch[1]));
    p.w = pkrtz(zsig(ch[2]), zsig(ch[3]));
    return __builtin_bit_cast(f16x8, p);
}

__global__ __launch_bounds__(256) void prep_kernel(
    const float* __restrict__ W1, const float* __restrict__ b1,
    const float* __restrict__ W2, const float* __restrict__ b2,
    const float* __restrict__ W3, const float* __restrict__ b3,
    const float* __restrict__ Wout, const float* __restrict__ bout,
    float* __restrict__ ws)
{
    const int tid = blockIdx.x * 256 + threadIdx.x;   // grid 26*256 = 6656
    if (tid < 5632) {                                 // 4 copies * 22 units * 64
        const int cpy = tid / 1408;
        const int r   = tid - cpy * 1408;
        const int u   = r >> 6, lane = r & 63;
        const int q = lane >> 4, l15 = lane & 15;
        float x[8];
        bool lo = false;
        #pragma unroll
        for (int e = 0; e < 8; ++e) {
            const int half = e >> 2, j = e & 3;
            float v;
            if (u < 2) {                       // W1: kt=0; frags mt = u*2+half
                const int mt = u * 2 + half;
                const int k = q * 4 + j;
                v = (k < 7) ? W1[k * 64 + mt * 16 + l15] * SCALE : 0.f;
            } else if (u < 10) {               // W2' = -2*W2*SCALE
                const int idx = u - 2, mt = idx >> 1, kp = idx & 1;
                const int k = (kp * 2 + half) * 16 + q * 4 + j;
                v = -2.0f * W2[k * 64 + mt * 16 + l15] * SCALE;
            } else if (u < 18) {               // W3' = -2*W3*SCALE
                const int idx = u - 10, mt = idx >> 1, kp = idx & 1;
                const int k = (kp * 2 + half) * 16 + q * 4 + j;
                v = -2.0f * W3[k * 64 + mt * 16 + l15] * SCALE;
            } else {                           // Wout' hi (18,19) / lo (20,21)
                const int kp = (u - 18) & 1;
                const int k = (kp * 2 + half) * 16 + q * 4 + j;
                v = (l15 < 3) ? -2.0f * Wout[k * 3 + l15] : 0.f;
                lo = (u >= 20);
            }
            x[e] = v;
        }
        u16 outw[8];
        #pragma unroll
        for (int e = 0; e < 8; ++e) {
            const f16 h = (f16)x[e];
            const f16 val = lo ? (f16)(x[e] - (float)h) : h;
            outw[e] = __builtin_bit_cast(u16, val);
        }
        uint4 g;
        g.x = outw[0] | ((u32)outw[1] << 16);
        g.y = outw[2] | ((u32)outw[3] << 16);
        g.z = outw[4] | ((u32)outw[5] << 16);
        g.w = outw[6] | ((u32)outw[7] << 16);
        *(uint4*)((char*)ws + (size_t)cpy * CPY_F * 4 + (size_t)(u * 64 + lane) * 16) = g;
    } else if (tid < 6412) {                   // biases: 4 copies * 195
        const int b = tid - 5632;
        const int cpy = b / 195, i = b - cpy * 195;
        if (i < 192) {
            const int Lb = i >> 6, j = i & 63;
            float bv;
            if (Lb == 0) {
                bv = b1[j];
            } else if (Lb == 1) {              // b2' = b2 + colsum(W2)
                bv = b2[j];
                for (int k = 0; k < 64; ++k) bv += W2[k * 64 + j];
            } else {                           // b3' = b3 + colsum(W3)
                bv = b3[j];
                for (int k = 0; k < 64; ++k) bv += W3[k * 64 + j];
            }
            ws[cpy * CPY_F + 5632 + i] = bv * SCALE;
        } else {                               // bout' = bout + colsum(Wout)
            const int c3 = i - 192;            // 0..2
            float bv = bout[c3];
            for (int k = 0; k < 64; ++k) bv += Wout[k * 3 + c3];
            ws[cpy * CPY_F + 5824 + c3] = bv;  // unscaled
        }
    }
}

__global__ __launch_bounds__(BLK, 2) void globe_mfma(
    const float* __restrict__ pts, const float* __restrict__ ctr,
    const float* __restrict__ nrm, const float* __restrict__ areas,
    const float* __restrict__ rlen, const float* __restrict__ bout,
    const float* __restrict__ p_scale, const float* __restrict__ p_bias,
    const float* __restrict__ v_scale, const float* __restrict__ v_bias,
    const float* __restrict__ ws,
    float* __restrict__ out)
{
    __shared__ __align__(16) u16 featL[2][2][64][8];   // [wave][stream]
    __shared__ __align__(16) uint4 geomL[2][2][64];
    __shared__ float xr[4];

    const int tid  = threadIdx.x;
    const int lane = tid & 63;
    const int wv   = tid >> 6;
    const int l15  = lane & 15;
    const int q    = lane >> 4;
    const int qf   = q & 1;                          // clamped feature octet
    const int t    = blockIdx.x;                     // both waves: same target

    const float px = pts[3 * t + 0], py = pts[3 * t + 1], pz = pts[3 * t + 2];
    const float invL0 = __builtin_amdgcn_rcpf(rlen[0]);
    const float invL1 = __builtin_amdgcn_rcpf(rlen[1]);
    f32x4 co_init = (f32x4){0.f, 0.f, 0.f, 0.f};
    if (q == 0) { co_init[0] = ws[5824]; co_init[1] = ws[5825]; co_init[2] = ws[5826]; }

    const f16x4 bz = (f16x4){0, 0, 0, 0};
    float accp = 0.f, avx = 0.f, avy = 0.f, avz = 0.f;

    const int stag = (wv + (int)blockIdx.x) & 1;     // phase stagger

    #pragma unroll 1
    for (int cc = 0; cc < 2; ++cc) {
        const int ch = cc ^ stag;
        // chunk-dependent weight copy (copies 0,2 used): defeats LICM
        const uint4* __restrict__ wsU = (const uint4*)ws + (ch * 2) * CPY_U;
        const float* __restrict__ wsBias = ws + (ch * 2) * CPY_F + 5632;

        // ---- features + geometry for BOTH streams ----
        #pragma unroll
        for (int st = 0; st < 2; ++st) {
            const int s = (wv * 4 + ch * 2 + st) * 64 + lane;
            const float cx = ctr[3 * s + 0], cy = ctr[3 * s + 1], cz = ctr[3 * s + 2];
            const float snx = nrm[3 * s + 0], sny = nrm[3 * s + 1], snz = nrm[3 * s + 2];
            const float ar = areas[s];
            const float rvx = px - cx, rvy = py - cy, rvz = pz - cz;
            const float r2 = rvx * rvx + rvy * rvy + rvz * rvz;
            const float r2e = r2 + 1e-8f;
            const float rinv = __builtin_amdgcn_rsqf(r2e);
            const float r = r2e * rinv;
            const float rhx = rvx * rinv, rhy = rvy * rinv, rhz = rvz * rinv;
            const float cth = rhx * snx + rhy * sny + rhz * snz;
            const float c2 = cth * cth;
            const float decay = ar * __builtin_amdgcn_rcpf(r2 + 1.0f);
            uint4 fw;
            fw.x = pkrtz(__builtin_amdgcn_rcpf(fmaf(r, invL0, 1.0f)),
                         __builtin_amdgcn_rcpf(fmaf(r, invL1, 1.0f)));
            fw.y = pkrtz(1.0f, cth);
            fw.z = pkrtz(fmaf(1.5f, c2, -0.5f), cth * fmaf(2.5f, c2, -1.5f));
            fw.w = pkrtz(__logf(ar), 0.0f);
            *(uint4*)&featL[wv][st][lane][0] = fw;
            uint4 g;
            g.x = __builtin_bit_cast(u32, decay);
            g.y = pkrtz(rhx, rhy);
            g.z = pkrtz(rhz, snx);
            g.w = pkrtz(sny, snz);
            geomL[wv][st][lane] = g;
        }

        // ---- layer 1 (16x16x16, K=7 padded; shared frags, both streams) ----
        f16x8 B2[2][2][4];   // [stream][kk][n4]  (K=32 z-frags for layer 2)
        {
            const uint4 g0 = wsU[0 * 64 + lane], g1 = wsU[1 * 64 + lane];
            f16x4 a1[4];
            a1[0] = lo4(g0); a1[1] = hi4(g0); a1[2] = lo4(g1); a1[3] = hi4(g1);
            float4 bv[4];
            #pragma unroll
            for (int mt = 0; mt < 4; ++mt)
                bv[mt] = *(const float4*)(wsBias + 0 * 64 + mt * 16 + q * 4);
            #pragma unroll
            for (int n4 = 0; n4 < 4; ++n4) {
                f16x4 bf[2];
                #pragma unroll
                for (int st = 0; st < 2; ++st) {
                    const f16x4 lv = *(const f16x4*)&featL[wv][st][n4 * 16 + l15][qf * 4];
                    bf[st] = (q < 2) ? lv : bz;
                }
                f32x4 c[2][4];
                #pragma unroll
                for (int mt = 0; mt < 4; ++mt) {
                    c[0][mt] = (f32x4){bv[mt].x, bv[mt].y, bv[mt].z, bv[mt].w};
                    c[1][mt] = c[0][mt];
                    c[0][mt] = mfma16(a1[mt], bf[0], c[0][mt]);
                    c[1][mt] = mfma16(a1[mt], bf[1], c[1][mt]);
                }
                #pragma unroll
                for (int kk = 0; kk < 2; ++kk) {
                    B2[0][kk][n4] = tpack8(c[0][2 * kk], c[0][2 * kk + 1]);
                    B2[1][kk][n4] = tpack8(c[1][2 * kk], c[1][2 * kk + 1]);
                }
            }
        }

        // ---- layer 2 (16x16x32) ----
        f16x8 B3[2][2][4];
        {
            f16x8 a[4][2];
            #pragma unroll
            for (int mt = 0; mt < 4; ++mt) {
                a[mt][0] = all8(wsU[(2 + 2 * mt) * 64 + lane]);
                a[mt][1] = all8(wsU[(3 + 2 * mt) * 64 + lane]);
            }
            float4 bv[4];
            #pragma unroll
            for (int mt = 0; mt < 4; ++mt)
                bv[mt] = *(const float4*)(wsBias + 1 * 64 + mt * 16 + q * 4);
            #pragma unroll
            for (int n4 = 0; n4 < 4; ++n4) {
                f32x4 c[2][4];
                #pragma unroll
                for (int mt = 0; mt < 4; ++mt) {
                    c[0][mt] = (f32x4){bv[mt].x, bv[mt].y, bv[mt].z, bv[mt].w};
                    c[1][mt] = c[0][mt];
                }
                #pragma unroll
                for (int kk = 0; kk < 2; ++kk)
                    #pragma unroll
                    for (int mt = 0; mt < 4; ++mt) {
                        c[0][mt] = mfma32(a[mt][kk], B2[0][kk][n4], c[0][mt]);
                        c[1][mt] = mfma32(a[mt][kk], B2[1][kk][n4], c[1][mt]);
                    }
                #pragma unroll
                for (int kk = 0; kk < 2; ++kk) {
                    B3[0][kk][n4] = tpack8(c[0][2 * kk], c[0][2 * kk + 1]);
                    B3[1][kk][n4] = tpack8(c[1][2 * kk], c[1][2 * kk + 1]);
                }
            }
        }

        // ---- layer 3 (16x16x32) ----
        f16x8 BO[2][2][4];
        {
            f16x8 a[4][2];
            #pragma unroll
            for (int mt = 0; mt < 4; ++mt) {
                a[mt][0] = all8(wsU[(10 + 2 * mt) * 64 + lane]);
                a[mt][1] = all8(wsU[(11 + 2 * mt) * 64 + lane]);
            }
            float4 bv[4];
            #pragma unroll
            for (int mt = 0; mt < 4; ++mt)
                bv[mt] = *(const float4*)(wsBias + 2 * 64 + mt * 16 + q * 4);
            #pragma unroll
            for (int n4 = 0; n4 < 4; ++n4) {
                f32x4 c[2][4];
                #pragma unroll
                for (int mt = 0; mt < 4; ++mt) {
                    c[0][mt] = (f32x4){bv[mt].x, bv[mt].y, bv[mt].z, bv[mt].w};
                    c[1][mt] = c[0][mt];
                }
                #pragma unroll
                for (int kk = 0; kk < 2; ++kk)
                    #pragma unroll
                    for (int mt = 0; mt < 4; ++mt) {
                        c[0][mt] = mfma32(a[mt][kk], B3[0][kk][n4], c[0][mt]);
                        c[1][mt] = mfma32(a[mt][kk], B3[1][kk][n4], c[1][mt]);
                    }
                #pragma unroll
                for (int kk = 0; kk < 2; ++kk) {
                    BO[0][kk][n4] = tpack8(c[0][2 * kk], c[0][2 * kk + 1]);
                    BO[1][kk][n4] = tpack8(c[1][2 * kk], c[1][2 * kk + 1]);
                }
            }
        }

        // ---- output layer (16x16x32, hi+lo) + decay-weighted accumulation ----
        {
            const f16x8 aoh0 = all8(wsU[18 * 64 + lane]);
            const f16x8 aoh1 = all8(wsU[19 * 64 + lane]);
            const f16x8 aol0 = all8(wsU[20 * 64 + lane]);
            const f16x8 aol1 = all8(wsU[21 * 64 + lane]);
            #pragma unroll
            for (int n4 = 0; n4 < 4; ++n4) {
                f32x4 co[2];
                co[0] = co_init; co[1] = co_init;
                co[0] = mfma32(aoh0, BO[0][0][n4], co[0]);
                co[1] = mfma32(aoh0, BO[1][0][n4], co[1]);
                co[0] = mfma32(aol0, BO[0][0][n4], co[0]);
                co[1] = mfma32(aol0, BO[1][0][n4], co[1]);
                co[0] = mfma32(aoh1, BO[0][1][n4], co[0]);
                co[1] = mfma32(aoh1, BO[1][1][n4], co[1]);
                co[0] = mfma32(aol1, BO[0][1][n4], co[0]);
                co[1] = mfma32(aol1, BO[1][1][n4], co[1]);
                if (q == 0) {
                    #pragma unroll
                    for (int st = 0; st < 2; ++st) {
                        const uint4 g = geomL[wv][st][n4 * 16 + l15];
                        const float d = __builtin_bit_cast(float, g.x);
                        const float2 rxy = __half22float2(__builtin_bit_cast(__half2, g.y));
                        const float2 rzx = __half22float2(__builtin_bit_cast(__half2, g.z));
                        const float2 nyz = __half22float2(__builtin_bit_cast(__half2, g.w));
                        const float o0 = co[st][0], o1 = co[st][1], o2 = co[st][2];
                        accp = fmaf(o0, d, accp);
                        avx  = fmaf(fmaf(o1, rxy.x, o2 * rzx.y), d, avx);
                        avy  = fmaf(fmaf(o1, rxy.y, o2 * nyz.x), d, avy);
                        avz  = fmaf(fmaf(o1, rzx.x, o2 * nyz.y), d, avz);
                    }
                }
            }
        }
    }

    // ---- reduce across the 16 accumulating lanes ----
    #pragma unroll
    for (int off = 8; off > 0; off >>= 1) {
        accp += __shfl_down(accp, off);
        avx  += __shfl_down(avx,  off);
        avy  += __shfl_down(avy,  off);
        avz  += __shfl_down(avz,  off);
    }

    // ---- cross-wave combine ----
    if (wv == 1 && lane == 0) {
        xr[0] = accp; xr[1] = avx; xr[2] = avy; xr[3] = avz;
    }
    __syncthreads();
    if (wv == 0 && lane == 0) {
        accp += xr[0]; avx += xr[1]; avy += xr[2]; avz += xr[3];
        const float ps = p_scale[0], pb = p_bias[0];
        const float vs = v_scale[0], vb = v_bias[0];
        out[4 * t + 0] = fmaf(accp, ps, pb);
        out[4 * t + 1] = fmaf(avx, vs, vb);
        out[4 * t + 2] = fmaf(avy, vs, vb);
        out[4 * t + 3] = fmaf(avz, vs, vb);
    }
}

extern "C" void kernel_launch(void* const* d_in, const int* in_sizes, int n_in,
                              void* d_out, int out_size, void* d_ws, size_t ws_size,
                              hipStream_t stream) {
    (void)in_sizes; (void)n_in; (void)ws_size; (void)out_size;
    const float* pts   = (const float*)d_in[0];
    const float* ctr   = (const float*)d_in[1];
    const float* nrm   = (const float*)d_in[2];
    const float* areas = (const float*)d_in[3];
    const float* rlen  = (const float*)d_in[4];
    const float* W1    = (const float*)d_in[5];
    const float* b1    = (const float*)d_in[6];
    const float* W2    = (const float*)d_in[7];
    const float* b2    = (const float*)d_in[8];
    const float* W3    = (const float*)d_in[9];
    const float* b3    = (const float*)d_in[10];
    const float* Wout  = (const float*)d_in[11];
    const float* bout  = (const float*)d_in[12];
    const float* ps    = (const float*)d_in[13];
    const float* pb    = (const float*)d_in[14];
    const float* vs    = (const float*)d_in[15];
    const float* vb    = (const float*)d_in[16];
    float* ws = (float*)d_ws;

    prep_kernel<<<26, 256, 0, stream>>>(W1, b1, W2, b2, W3, b3, Wout, bout, ws);
    globe_mfma<<<N_T, BLK, 0, stream>>>(
        pts, ctr, nrm, areas, rlen, bout, ps, pb, vs, vb, ws, (float*)d_out);
}